// Round 13
// baseline (229.863 us; speedup 1.0000x reference)
//
#include <hip/hip_runtime.h>

typedef unsigned short u16;
typedef unsigned int u32;
typedef __bf16 bf16x8 __attribute__((ext_vector_type(8)));
typedef unsigned short ushort8 __attribute__((ext_vector_type(8)));
typedef float floatx4 __attribute__((ext_vector_type(4)));
typedef u32 u32x2 __attribute__((ext_vector_type(2)));

#define S_LEN 2048
#define NH 32
#define NKV 8
#define HD_ 64
#define LDQ 3072   // qkv row stride: [q 0..2047 | k 2048..2559 | v 2560..3071]

__device__ __forceinline__ u16 f2bf(float f) {
  unsigned u = __builtin_bit_cast(unsigned, f);
  u += 0x7FFF + ((u >> 16) & 1);   // round-to-nearest-even
  return (u16)(u >> 16);
}
__device__ __forceinline__ float bf2f(u16 h) {
  unsigned u = ((unsigned)h) << 16;
  return __builtin_bit_cast(float, u);
}
__device__ __forceinline__ bf16x8 ld8(const u16* p) {
  return __builtin_bit_cast(bf16x8, *(const ushort8*)p);
}
__device__ __forceinline__ floatx4 mfma16(bf16x8 a, bf16x8 b, floatx4 c) {
  return __builtin_amdgcn_mfma_f32_16x16x32_bf16(a, b, c, 0, 0, 0);
}
// two fp32 -> packed bf16 pair (round-half-up via +0x8000, then byte-perm)
__device__ __forceinline__ u32 pk2bf(float a, float b) {
  u32 ua = __builtin_bit_cast(u32, a) + 0x8000u;
  u32 ub = __builtin_bit_cast(u32, b) + 0x8000u;
  return __builtin_amdgcn_perm(ub, ua, 0x07060302);   // [bf(a) | bf(b)<<16]
}

// ---------------- fp32 -> bf16 convert (vectorized, dense) ----------------
// r12: r11's channel-padded variant REGRESSED (QKV 43.6 -> 51.0us, FETCH unchanged)
// — channel-conflict theory falsified; reverted to dense strides everywhere.
__global__ void cvt_kernel(const float* __restrict__ in, u16* __restrict__ out, int n4) {
  int i = blockIdx.x * blockDim.x + threadIdx.x;
  if (i >= n4) return;
  float4 v = ((const float4*)in)[i];
  ((ushort4*)out)[i] = make_ushort4(f2bf(v.x), f2bf(v.y), f2bf(v.z), f2bf(v.w));
}

// ---------------- Double-buffered GEMM: C[M][N] = A[M][K] @ B[N][K]^T (bf16 in) ------------
// TM x TN tile, BK=64, 4 waves (2x2). Single barrier per K-iter. LDS chunk-XOR swizzle:
// conflict-free (measured 0). REG-STAGED (r6 lesson): prefetch covered by one full
// compute phase. XCD-chunked block swizzle (r9, 512 blocks = 64/XCD, bijective).
// r12/r13: ROPE fused into the epilogue (QKV instance only). C-write cols are
// lane-adjacent (col = ..+l16), so the rope pair (2d,2d+1) sits in lanes l and l^1:
// one __shfl_xor(v,1) delivers the partner; out = (v*c ± pv*sn) * scale, even/odd.
// q cols (<2048) get the log2e/sqrt(HD) pre-scale; k cols (<2560) scale 1; v cols
// pass through. Cost ~48 shfl + 24x8B fc loads per thread, ONCE per block (amortized
// over 32 K-iters) — deletes both rope launches (2 graph nodes) and one bf16
// rounding step (rope now rotates the fp32 accumulator pre-rounding).
// (r13 = r12 resubmitted verbatim: the r12 run died in the broker, "container failed
// twice", before any GPU execution — no evidence against the kernel.)
template <int TM, int TN, int OUT_BF16, int ROPE>
__global__ __launch_bounds__(256) void gemm_db(
    const u16* __restrict__ A, const u16* __restrict__ B, void* __restrict__ C,
    const float* __restrict__ fc, int ldc, int K, int lda) {
  __shared__ __align__(16) u16 As[2][TM * 64];
  __shared__ __align__(16) u16 Bs[2][TN * 64];
  const int tid = threadIdx.x;
  const int wave = tid >> 6, lane = tid & 63;
  const int quad = lane >> 4, l16 = lane & 15;
  const int nwg = gridDim.x * gridDim.y;
  int lin = (int)blockIdx.y * gridDim.x + blockIdx.x;
  lin = (lin & 7) * (nwg >> 3) + (lin >> 3);     // XCD-chunked bijective remap
  const int bm = (lin % gridDim.y) * TM, bn = (lin / gridDim.y) * TN;
  const int wr = (wave >> 1) * (TM / 2), wc = (wave & 1) * (TN / 2);
  constexpr int MI = TM / 32, NI = TN / 32;
  const int crow = tid >> 3, col8 = tid & 7;     // staging: row base, 8-elem col chunk

  size_t aoff[MI], boff[NI];
#pragma unroll
  for (int j = 0; j < MI; j++) aoff[j] = (size_t)(bm + crow + j * 32) * lda + col8 * 8;
#pragma unroll
  for (int j = 0; j < NI; j++) boff[j] = (size_t)(bn + crow + j * 32) * K + col8 * 8;

  ushort8 a8[MI], b8[NI];
  auto load_tiles = [&](int k0) {
#pragma unroll
    for (int j = 0; j < MI; j++) a8[j] = *(const ushort8*)(A + aoff[j] + k0);
#pragma unroll
    for (int j = 0; j < NI; j++) b8[j] = *(const ushort8*)(B + boff[j] + k0);
  };
  auto write_tiles = [&](int p) {
#pragma unroll
    for (int j = 0; j < MI; j++) {
      const int row = crow + j * 32;
      *(ushort8*)&As[p][row * 64 + ((col8 ^ (row & 7)) * 8)] = a8[j];
    }
#pragma unroll
    for (int j = 0; j < NI; j++) {
      const int row = crow + j * 32;
      *(ushort8*)&Bs[p][row * 64 + ((col8 ^ (row & 7)) * 8)] = b8[j];
    }
  };

  floatx4 acc[MI][NI] = {};
  load_tiles(0);
  write_tiles(0);
  __syncthreads();
  int p = 0;
  for (int k0 = 0; k0 < K; k0 += 64) {
    const bool more = (k0 + 64 < K);
    if (more) load_tiles(k0 + 64);               // prefetch next tile (covered by compute)
#pragma unroll
    for (int kh = 0; kh < 2; kh++) {
      bf16x8 af[MI], bfr[NI];
#pragma unroll
      for (int mi = 0; mi < MI; mi++) {
        const int row = wr + mi * 16 + l16;
        af[mi] = ld8(&As[p][row * 64 + (((kh * 4 + quad) ^ (row & 7)) * 8)]);
      }
#pragma unroll
      for (int ni = 0; ni < NI; ni++) {
        const int row = wc + ni * 16 + l16;
        bfr[ni] = ld8(&Bs[p][row * 64 + (((kh * 4 + quad) ^ (row & 7)) * 8)]);
      }
#pragma unroll
      for (int mi = 0; mi < MI; mi++)
#pragma unroll
        for (int ni = 0; ni < NI; ni++)
          acc[mi][ni] = mfma16(af[mi], bfr[ni], acc[mi][ni]);
    }
    if (more) {
      write_tiles(p ^ 1);                        // vmcnt wait lands here, post-compute
      __syncthreads();                           // one barrier per iter
      p ^= 1;
    }
  }

#pragma unroll
  for (int mi = 0; mi < MI; mi++)
#pragma unroll
    for (int ni = 0; ni < NI; ni++) {
      const int col = bn + wc + ni * 16 + l16;
#pragma unroll
      for (int r = 0; r < 4; r++) {
        const int row = bm + wr + mi * 16 + quad * 4 + r;   // C/D: row=(lane>>4)*4+reg
        float v = acc[mi][ni][r];
        if (ROPE) {
          // rope pair partner lives in lane^1 (adjacent col); fc[s][d] = {cos, sin}
          float pv = __shfl_xor(v, 1);
          if (col < 2560) {
            const int dp = (col & 63) >> 1;
            const float c  = fc[row * 64 + dp * 2];
            const float sn = fc[row * 64 + dp * 2 + 1];
            const float scale = (col < 2048) ? 0.18033688f : 1.0f;  // q: log2e/sqrt(HD)
            v = (col & 1) ? (v * c + pv * sn) * scale    // odd  = x0*sn + x1*c
                          : (v * c - pv * sn) * scale;   // even = x0*c  - x1*sn
          }
        }
        if (OUT_BF16) ((u16*)C)[(size_t)row * ldc + col] = f2bf(v);
        else          ((float*)C)[(size_t)row * ldc + col] = v;
      }
    }
}

// ---------------- V transpose: qkv[s][2560 + g*64+hd] -> vT[(g*64+hd)][s] ----------------
__global__ void transpose_v(const u16* __restrict__ qkv, u16* __restrict__ vT) {
  int idx = blockIdx.x * blockDim.x + threadIdx.x;   // over KV*HD*S
  int s = idx & (S_LEN - 1);
  int t = idx >> 11;                                 // g*64+hd
  vT[idx] = qkv[(size_t)s * LDQ + 2560 + t];
}

// ---------------- Flash attention (causal, GQA) — r5 structure (measured best) ------------
// r2's two-phase uniform schedule (block (h,p) runs q-tiles p then 31-p, exactly 33 iters
// per block) + r3's conflict-free chunk-XOR stride-64 LDS + K/V double-buffer with ONE RAW
// s_barrier per iter (lgkmcnt(0) only; prefetch global_loads are register-destined and
// stay in flight across the barrier).
__global__ __launch_bounds__(256) void attn_kernel(const u16* qkv, const u16* __restrict__ vT,
                                                   u16* __restrict__ o) {
  __shared__ __align__(16) u16 Ks[2][64 * 64];   // [key][hd], chunk-XOR swizzled
  __shared__ __align__(16) u16 Vs[2][64 * 64];   // [hd][key], chunk-XOR swizzled
  __shared__ __align__(16) u16 pS[4][16 * 64];   // per-wave P^T scratch (reused A/B)
  const int h = blockIdx.x;
  const int g = h >> 2;                          // kv head
  const int tid = threadIdx.x;
  const int wave = tid >> 6, lane = tid & 63;
  const int quad = lane >> 4, l16 = lane & 15;
  const int p_ = (int)blockIdx.y;                // 0..15
  const int qtB = 31 - p_;                       // pair (p_, 31-p_): 33 iters total

  const ushort8 ones_u = {0x3F80, 0x3F80, 0x3F80, 0x3F80, 0x3F80, 0x3F80, 0x3F80, 0x3F80};
  const bf16x8 onesA = __builtin_bit_cast(bf16x8, ones_u);

  const int qrow = wave * 16 + l16;
  const int qgA = p_ * 64 + qrow, qgB = qtB * 64 + qrow;
  const size_t qoffA = (size_t)qgA * LDQ + h * HD_;
  const size_t qoffB = (size_t)qgB * LDQ + h * HD_;
  bf16x8 qfA0 = ld8(qkv + qoffA + quad * 8);     // B-frag: n=q, k=hd (pre-scaled log2e/8)
  bf16x8 qfA1 = ld8(qkv + qoffA + 32 + quad * 8);
  bf16x8 qfB0 = ld8(qkv + qoffB + quad * 8);
  bf16x8 qfB1 = ld8(qkv + qoffB + 32 + quad * 8);

  // staging: thread owns rows {rs0, rs0+32}, chunk col8; swizzled slot col8^(row&7)
  const int rs0 = tid >> 3, rs1 = rs0 + 32;
  const int col8 = tid & 7;
  const int so = (col8 ^ (rs0 & 7)) * 8;         // swizzled u16 offset within row
  const int o0 = col8 * 8;                       // global col offset
  // lane-constant swizzled chunk offsets for all frag reads (chunks quad and 4+quad)
  const int x0 = (quad ^ (l16 & 7)) * 8;
  const int x1 = ((4 + quad) ^ (l16 & 7)) * 8;
  const u16* ksrc = qkv + 2048 + g * HD_;        // row stride LDQ
  const u16* vsrc = vT + (size_t)g * HD_ * S_LEN;// row stride S_LEN

  ushort8 kp0, kp1, vp0, vp1;
  auto gload = [&](int t) {                      // tile t -> regs
    const int tb = t * 64;
    kp0 = *(const ushort8*)(ksrc + (size_t)(tb + rs0) * LDQ + o0);
    kp1 = *(const ushort8*)(ksrc + (size_t)(tb + rs1) * LDQ + o0);
    vp0 = *(const ushort8*)(vsrc + (size_t)rs0 * S_LEN + tb + o0);
    vp1 = *(const ushort8*)(vsrc + (size_t)rs1 * S_LEN + tb + o0);
  };
  auto tile_of = [&](int i) { return (i <= p_) ? i : (i - p_ - 1); };

  u16* myP = &pS[wave][0];
  int pp = 0;

  // prologue: stage tile 0 -> buf0; prefetch tile_of(1) -> regs
  gload(0);
  *(ushort8*)&Ks[0][rs0 * 64 + so] = kp0;
  *(ushort8*)&Ks[0][rs1 * 64 + so] = kp1;
  *(ushort8*)&Vs[0][rs0 * 64 + so] = vp0;
  *(ushort8*)&Vs[0][rs1 * 64 + so] = vp1;
  gload(tile_of(1));
  __syncthreads();

  auto phase = [&](int qt, int qg, bf16x8 q0, bf16x8 q1, int ibase) {
    floatx4 O[4] = {};                           // O^T: row=hd(nt*16+quad*4+r), col=q(l16)
    floatx4 lac = {};                            // l via MFMA ones-row
    for (int kt = 0; kt <= qt; kt++) {
      const int i = ibase + kt;                  // global iter 0..32
      const u16* Kc = &Ks[pp][0];
      const u16* Vc = &Vs[pp][0];

      // ---- K frags from current buffer ----
      bf16x8 kf[4][2];
#pragma unroll
      for (int sub = 0; sub < 4; sub++) {
        const u16* kb = Kc + (sub * 16 + l16) * 64;
        kf[sub][0] = ld8(kb + x0);
        kf[sub][1] = ld8(kb + x1);
      }
      // ---- stage next tile into buf pp^1; prefetch tile after next ----
      if (i < 32) {
        *(ushort8*)&Ks[pp ^ 1][rs0 * 64 + so] = kp0;
        *(ushort8*)&Ks[pp ^ 1][rs1 * 64 + so] = kp1;
        *(ushort8*)&Vs[pp ^ 1][rs0 * 64 + so] = vp0;
        *(ushort8*)&Vs[pp ^ 1][rs1 * 64 + so] = vp1;
        if (i < 31) gload(tile_of(i + 2));
      }
      // ---- S^T = K*Q^T : 4 sub-tiles of 16 keys ----
      floatx4 sf[4];
#pragma unroll
      for (int sub = 0; sub < 4; sub++) {
        floatx4 s = {};
        s = mfma16(kf[sub][0], q0, s);           // A-frag: m=key, k=hd
        s = mfma16(kf[sub][1], q1, s);
        sf[sub] = s;
      }
      if (kt == qt) {                            // diagonal tile: mask key > q
#pragma unroll
        for (int sub = 0; sub < 4; sub++)
#pragma unroll
          for (int r = 0; r < 4; r++)
            if (kt * 64 + sub * 16 + quad * 4 + r > qg) sf[sub][r] = -INFINITY;
      }
      // ---- P = exp2(s'), pack to bf16 pairs ----
      u32x2 pk[4];
#pragma unroll
      for (int sub = 0; sub < 4; sub++) {
        pk[sub].x = pk2bf(__builtin_amdgcn_exp2f(sf[sub][0]), __builtin_amdgcn_exp2f(sf[sub][1]));
        pk[sub].y = pk2bf(__builtin_amdgcn_exp2f(sf[sub][2]), __builtin_amdgcn_exp2f(sf[sub][3]));
      }
      // ---- V frags from current buffer ----
      bf16x8 vf[4][2];
#pragma unroll
      for (int nt = 0; nt < 4; nt++) {
        const u16* vb = Vc + (nt * 16 + l16) * 64;
        vf[nt][0] = ld8(vb + x0);
        vf[nt][1] = ld8(vb + x1);
      }
      // ---- P^T to per-wave LDS scratch (swizzled b64 stores) ----
#pragma unroll
      for (int sub = 0; sub < 4; sub++) {
        const int slot = (2 * sub + (quad >> 1)) ^ (l16 & 7);
        *(u32x2*)&myP[l16 * 64 + slot * 8 + (quad & 1) * 4] = pk[sub];
      }
      asm volatile("s_waitcnt lgkmcnt(0)" ::: "memory");  // wave-local LDS write->read fence
      bf16x8 pf0 = ld8(&myP[l16 * 64 + x0]);     // B-frag: n=q, k=key 0..31
      bf16x8 pf1 = ld8(&myP[l16 * 64 + x1]);     //                key 32..63
      // ---- O^T += V^T * P^T ; l += ones * P^T (matrix pipe) ----
#pragma unroll
      for (int nt = 0; nt < 4; nt++) {
        O[nt] = mfma16(vf[nt][0], pf0, O[nt]);
        O[nt] = mfma16(vf[nt][1], pf1, O[nt]);
      }
      lac = mfma16(onesA, pf0, lac);
      lac = mfma16(onesA, pf1, lac);

      if (i < 32) {
        // LDS must be drained before waves cross (staging visibility); the prefetch
        // global_loads are register-destined and stay IN FLIGHT across the barrier.
        asm volatile("s_waitcnt lgkmcnt(0)" ::: "memory");
        __builtin_amdgcn_s_barrier();
        pp ^= 1;
      }
    }
    const float inv = 1.0f / lac[0];
    const size_t ooff = (size_t)qg * 2048 + h * HD_;
#pragma unroll
    for (int nt = 0; nt < 4; nt++)
#pragma unroll
      for (int r = 0; r < 4; r++)
        o[ooff + nt * 16 + quad * 4 + r] = f2bf(O[nt][r] * inv);
  };

  phase(p_, qgA, qfA0, qfA1, 0);                 // q-tile p_   (kt = 0..p_)
  phase(qtB, qgB, qfB0, qfB1, p_ + 1);           // q-tile 31-p_ (kt = 0..31-p_)
}

extern "C" void kernel_launch(void* const* d_in, const int* in_sizes, int n_in,
                              void* d_out, int out_size, void* d_ws, size_t ws_size,
                              hipStream_t stream) {
  const float* x  = (const float*)d_in[0];
  const float* fc = (const float*)d_in[1];
  const float* wq = (const float*)d_in[2];
  const float* wk = (const float*)d_in[3];
  const float* wv = (const float*)d_in[4];
  const float* wo = (const float*)d_in[5];
  float* out = (float*)d_out;

  // Workspace (30 MB), r9 layout. Lifetimes:
  //   [0,12)MB  qkv bf16: 2048 x 3072 (q|k|v), written ROPE'D by the QKV gemm epilogue
  //   [12,24)MB wb bf16: wq|wk|wv (3072 x 2048) — dead after QKV gemm
  //   [12,14)MB vT bf16 (after wb dead)
  //   [14,22)MB wob bf16 (cvt'd after QKV gemm)
  //   [22,30)MB ob bf16: attention output
  // x bf16 (8 MB) lives in d_out (16.8 MB) — overwritten by the final O-GEMM.
  char* ws = (char*)d_ws;
  const size_t MB = 1024 * 1024;
  u16* qkv = (u16*)(ws);
  u16* wb  = (u16*)(ws + 12 * MB);
  u16* vTb = (u16*)(ws + 12 * MB);
  u16* wob = (u16*)(ws + 14 * MB);
  u16* ob  = (u16*)(ws + 22 * MB);
  u16* xb  = (u16*)d_out;
  (void)ws_size; (void)n_in; (void)in_sizes; (void)out_size;

  // 1) x, wq|wk|wv -> bf16 (dense)
  cvt_kernel<<<4096, 256, 0, stream>>>(x,  xb, 1048576);
  cvt_kernel<<<4096, 256, 0, stream>>>(wq, wb, 1048576);
  cvt_kernel<<<1024, 256, 0, stream>>>(wk, wb + (size_t)2048 * 2048, 262144);
  cvt_kernel<<<1024, 256, 0, stream>>>(wv, wb + (size_t)2560 * 2048, 262144);
  // 2) fused QKV projection + RoPE epilogue (128x96, 512 blocks = 2/CU, XCD swizzle)
  gemm_db<128, 96, 1, 1><<<dim3(32, 16), 256, 0, stream>>>(xb, wb, qkv, fc, LDQ, 2048, 2048);
  // 3) wo -> bf16 (wb region dead now)
  cvt_kernel<<<4096, 256, 0, stream>>>(wo, wob, 1048576);
  // 4) V transpose (v cols are rope-free; q/k already roped by the gemm epilogue)
  transpose_v<<<4096, 256, 0, stream>>>(qkv, vTb);
  // 5) causal GQA flash attention -> ob (512 uniform 33-iter blocks, two-phase)
  attn_kernel<<<dim3(NH, 16), 256, 0, stream>>>(qkv, vTb, ob);
  // 6) output projection (128x64, 512 blocks, fp32 out, XCD swizzle) — overwrites xb
  gemm_db<128, 64, 0, 0><<<dim3(32, 16), 256, 0, stream>>>(ob, wob, out, nullptr, 2048, 2048, 2048);
}

// Round 14
// 215.162 us; speedup vs baseline: 1.0683x; 1.0683x over previous
//
#include <hip/hip_runtime.h>

typedef unsigned short u16;
typedef unsigned int u32;
typedef __bf16 bf16x8 __attribute__((ext_vector_type(8)));
typedef unsigned short ushort8 __attribute__((ext_vector_type(8)));
typedef float floatx4 __attribute__((ext_vector_type(4)));
typedef u32 u32x2 __attribute__((ext_vector_type(2)));

#define S_LEN 2048
#define NH 32
#define NKV 8
#define HD_ 64
#define LDQ 3072   // qkv row stride: [q 0..2047 | k 2048..2559 | v 2560..3071]

__device__ __forceinline__ u16 f2bf(float f) {
  unsigned u = __builtin_bit_cast(unsigned, f);
  u += 0x7FFF + ((u >> 16) & 1);   // round-to-nearest-even
  return (u16)(u >> 16);
}
__device__ __forceinline__ float bf2f(u16 h) {
  unsigned u = ((unsigned)h) << 16;
  return __builtin_bit_cast(float, u);
}
__device__ __forceinline__ bf16x8 ld8(const u16* p) {
  return __builtin_bit_cast(bf16x8, *(const ushort8*)p);
}
__device__ __forceinline__ floatx4 mfma16(bf16x8 a, bf16x8 b, floatx4 c) {
  return __builtin_amdgcn_mfma_f32_16x16x32_bf16(a, b, c, 0, 0, 0);
}
// two fp32 -> packed bf16 pair (round-half-up via +0x8000, then byte-perm)
__device__ __forceinline__ u32 pk2bf(float a, float b) {
  u32 ua = __builtin_bit_cast(u32, a) + 0x8000u;
  u32 ub = __builtin_bit_cast(u32, b) + 0x8000u;
  return __builtin_amdgcn_perm(ub, ua, 0x07060302);   // [bf(a) | bf(b)<<16]
}

// ---------------- fp32 -> bf16 convert (vectorized, dense) ----------------
__global__ void cvt_kernel(const float* __restrict__ in, u16* __restrict__ out, int n4) {
  int i = blockIdx.x * blockDim.x + threadIdx.x;
  if (i >= n4) return;
  float4 v = ((const float4*)in)[i];
  ((ushort4*)out)[i] = make_ushort4(f2bf(v.x), f2bf(v.y), f2bf(v.z), f2bf(v.w));
}

// ---------------- Double-buffered GEMM: C[M][N] = A[M][K] @ B[N][K]^T (bf16 in) ------------
// r14: 8-WAVE (512-thread) blocks at the same 128x96 / 128x64 tiles. The 4-wave version
// was 4x stall-dominated (3.4Kcy/iter vs ~400cy/wave of issue work) with only 2 waves/SIMD
// to hide the vmcnt->ds_write->barrier->lgkm chain; locality levers all failed (swizzle
// +4%, pad -15%, DMA -11%) because TLP, not locality, is the deficit. LDS unchanged
// (57KB -> still 2 blocks/CU), so waves/CU doubles: 8 -> 16 (4/SIMD). Wave grid 4x2:
// wr=(wave>>1)*(TM/4), wc=(wave&1)*(TN/2); per-wave acc (TM/64)x(TN/32). Staging: 512
// threads, thread t owns rows {crow, crow+64} (A) / {crow [, crow+64 if TN>64]} (B),
// boundary crow<32 <=> waves 0-3 (wave-uniform). Fusion into this kernel is known-bad
// (r10 fp32-staging 2x; r13 rope epilogue +35% via regalloc) — keep it pure.
// Chunk-XOR LDS swizzle (conflict-free, measured 0), reg-staged prefetch, one barrier
// per iter, XCD-chunked block swizzle (512 blocks = 64/XCD, bijective) all retained.
template <int TM, int TN, int OUT_BF16>
__global__ __launch_bounds__(512) void gemm_db(
    const u16* __restrict__ A, const u16* __restrict__ B, void* __restrict__ C,
    int ldc, int K, int lda) {
  __shared__ __align__(16) u16 As[2][TM * 64];
  __shared__ __align__(16) u16 Bs[2][TN * 64];
  const int tid = threadIdx.x;
  const int wave = tid >> 6, lane = tid & 63;
  const int quad = lane >> 4, l16 = lane & 15;
  const int nwg = gridDim.x * gridDim.y;
  int lin = (int)blockIdx.y * gridDim.x + blockIdx.x;
  lin = (lin & 7) * (nwg >> 3) + (lin >> 3);     // XCD-chunked bijective remap
  const int bm = (lin % gridDim.y) * TM, bn = (lin / gridDim.y) * TN;
  const int wr = (wave >> 1) * (TM / 4);         // 4 wave-rows of TM/4
  const int wc = (wave & 1) * (TN / 2);          // 2 wave-cols of TN/2
  constexpr int MI = TM / 64, NI = TN / 32;      // per-wave 16x16 frags: MI x NI
  constexpr int BX = (TN > 64) ? 1 : 0;          // B second staging group exists?
  const int crow = tid >> 3, col8 = tid & 7;     // staging: row 0..63, 8-elem col chunk

  size_t aoff[2], boff[2];
#pragma unroll
  for (int j = 0; j < 2; j++) aoff[j] = (size_t)(bm + crow + j * 64) * lda + col8 * 8;
  boff[0] = (size_t)(bn + crow) * K + col8 * 8;
  boff[1] = (size_t)(bn + crow + 64) * K + col8 * 8;   // only used when crow < TN-64
  const bool bAct = BX && (crow < TN - 64);      // wave-uniform: crow<32 <=> waves 0..3

  ushort8 a8[2], b8[2];
  auto load_tiles = [&](int k0) {
#pragma unroll
    for (int j = 0; j < 2; j++) a8[j] = *(const ushort8*)(A + aoff[j] + k0);
    b8[0] = *(const ushort8*)(B + boff[0] + k0);
    if (bAct) b8[1] = *(const ushort8*)(B + boff[1] + k0);
  };
  const int sw = (col8 ^ (crow & 7)) * 8;        // swizzled chunk (same for row, row+64)
  auto write_tiles = [&](int p) {
#pragma unroll
    for (int j = 0; j < 2; j++)
      *(ushort8*)&As[p][(crow + j * 64) * 64 + sw] = a8[j];
    *(ushort8*)&Bs[p][crow * 64 + sw] = b8[0];
    if (bAct) *(ushort8*)&Bs[p][(crow + 64) * 64 + sw] = b8[1];
  };

  floatx4 acc[MI][NI] = {};
  load_tiles(0);
  write_tiles(0);
  __syncthreads();
  int p = 0;
  for (int k0 = 0; k0 < K; k0 += 64) {
    const bool more = (k0 + 64 < K);
    if (more) load_tiles(k0 + 64);               // prefetch next tile (covered by compute)
#pragma unroll
    for (int kh = 0; kh < 2; kh++) {
      bf16x8 af[MI], bfr[NI];
#pragma unroll
      for (int mi = 0; mi < MI; mi++) {
        const int row = wr + mi * 16 + l16;
        af[mi] = ld8(&As[p][row * 64 + (((kh * 4 + quad) ^ (row & 7)) * 8)]);
      }
#pragma unroll
      for (int ni = 0; ni < NI; ni++) {
        const int row = wc + ni * 16 + l16;
        bfr[ni] = ld8(&Bs[p][row * 64 + (((kh * 4 + quad) ^ (row & 7)) * 8)]);
      }
#pragma unroll
      for (int mi = 0; mi < MI; mi++)
#pragma unroll
        for (int ni = 0; ni < NI; ni++)
          acc[mi][ni] = mfma16(af[mi], bfr[ni], acc[mi][ni]);
    }
    if (more) {
      write_tiles(p ^ 1);                        // vmcnt wait lands here, post-compute
      __syncthreads();                           // one barrier per iter
      p ^= 1;
    }
  }

#pragma unroll
  for (int mi = 0; mi < MI; mi++)
#pragma unroll
    for (int ni = 0; ni < NI; ni++)
#pragma unroll
      for (int r = 0; r < 4; r++) {
        const int row = bm + wr + mi * 16 + quad * 4 + r;   // C/D: row=(lane>>4)*4+reg
        const int col = bn + wc + ni * 16 + l16;            //      col=lane&15
        if (OUT_BF16) ((u16*)C)[(size_t)row * ldc + col] = f2bf(acc[mi][ni][r]);
        else          ((float*)C)[(size_t)row * ldc + col] = acc[mi][ni][r];
      }
}

// ---------------- RoPE in-place on bf16, rows of `row_stride`, nheads = 1<<h_bits ----------------
// r14: standalone again — r13's gemm-epilogue fusion cost +15us on the gemm (regalloc
// perturbation of the inner loop) vs ~12us of launch savings. Net negative; reverted.
__global__ void rope_kernel(u16* __restrict__ qk, const float* __restrict__ fc, int h_bits,
                            int row_stride, float scale) {
  int idx = blockIdx.x * blockDim.x + threadIdx.x;   // over S * nheads * 32 pairs
  int d = idx & 31;
  int t = idx >> 5;
  int hh = t & ((1 << h_bits) - 1);
  int s = t >> h_bits;
  float c  = fc[s * 64 + d * 2];
  float sn = fc[s * 64 + d * 2 + 1];
  size_t base = (size_t)s * row_stride + hh * 64 + d * 2;
  float x0 = bf2f(qk[base]), x1 = bf2f(qk[base + 1]);
  qk[base]     = f2bf((x0 * c - x1 * sn) * scale);
  qk[base + 1] = f2bf((x0 * sn + x1 * c) * scale);
}

// ---------------- V transpose: qkv[s][2560 + g*64+hd] -> vT[(g*64+hd)][s] ----------------
__global__ void transpose_v(const u16* __restrict__ qkv, u16* __restrict__ vT) {
  int idx = blockIdx.x * blockDim.x + threadIdx.x;   // over KV*HD*S
  int s = idx & (S_LEN - 1);
  int t = idx >> 11;                                 // g*64+hd
  vT[idx] = qkv[(size_t)s * LDQ + 2560 + t];
}

// ---------------- Flash attention (causal, GQA) — r5 structure (measured best) ------------
// r2's two-phase uniform schedule (block (h,p) runs q-tiles p then 31-p, exactly 33 iters
// per block) + r3's conflict-free chunk-XOR stride-64 LDS + K/V double-buffer with ONE RAW
// s_barrier per iter (lgkmcnt(0) only; prefetch global_loads are register-destined and
// stay in flight across the barrier).
__global__ __launch_bounds__(256) void attn_kernel(const u16* qkv, const u16* __restrict__ vT,
                                                   u16* __restrict__ o) {
  __shared__ __align__(16) u16 Ks[2][64 * 64];   // [key][hd], chunk-XOR swizzled
  __shared__ __align__(16) u16 Vs[2][64 * 64];   // [hd][key], chunk-XOR swizzled
  __shared__ __align__(16) u16 pS[4][16 * 64];   // per-wave P^T scratch (reused A/B)
  const int h = blockIdx.x;
  const int g = h >> 2;                          // kv head
  const int tid = threadIdx.x;
  const int wave = tid >> 6, lane = tid & 63;
  const int quad = lane >> 4, l16 = lane & 15;
  const int p_ = (int)blockIdx.y;                // 0..15
  const int qtB = 31 - p_;                       // pair (p_, 31-p_): 33 iters total

  const ushort8 ones_u = {0x3F80, 0x3F80, 0x3F80, 0x3F80, 0x3F80, 0x3F80, 0x3F80, 0x3F80};
  const bf16x8 onesA = __builtin_bit_cast(bf16x8, ones_u);

  const int qrow = wave * 16 + l16;
  const int qgA = p_ * 64 + qrow, qgB = qtB * 64 + qrow;
  const size_t qoffA = (size_t)qgA * LDQ + h * HD_;
  const size_t qoffB = (size_t)qgB * LDQ + h * HD_;
  bf16x8 qfA0 = ld8(qkv + qoffA + quad * 8);     // B-frag: n=q, k=hd (pre-scaled log2e/8)
  bf16x8 qfA1 = ld8(qkv + qoffA + 32 + quad * 8);
  bf16x8 qfB0 = ld8(qkv + qoffB + quad * 8);
  bf16x8 qfB1 = ld8(qkv + qoffB + 32 + quad * 8);

  // staging: thread owns rows {rs0, rs0+32}, chunk col8; swizzled slot col8^(row&7)
  const int rs0 = tid >> 3, rs1 = rs0 + 32;
  const int col8 = tid & 7;
  const int so = (col8 ^ (rs0 & 7)) * 8;         // swizzled u16 offset within row
  const int o0 = col8 * 8;                       // global col offset
  // lane-constant swizzled chunk offsets for all frag reads (chunks quad and 4+quad)
  const int x0 = (quad ^ (l16 & 7)) * 8;
  const int x1 = ((4 + quad) ^ (l16 & 7)) * 8;
  const u16* ksrc = qkv + 2048 + g * HD_;        // row stride LDQ
  const u16* vsrc = vT + (size_t)g * HD_ * S_LEN;// row stride S_LEN

  ushort8 kp0, kp1, vp0, vp1;
  auto gload = [&](int t) {                      // tile t -> regs
    const int tb = t * 64;
    kp0 = *(const ushort8*)(ksrc + (size_t)(tb + rs0) * LDQ + o0);
    kp1 = *(const ushort8*)(ksrc + (size_t)(tb + rs1) * LDQ + o0);
    vp0 = *(const ushort8*)(vsrc + (size_t)rs0 * S_LEN + tb + o0);
    vp1 = *(const ushort8*)(vsrc + (size_t)rs1 * S_LEN + tb + o0);
  };
  auto tile_of = [&](int i) { return (i <= p_) ? i : (i - p_ - 1); };

  u16* myP = &pS[wave][0];
  int pp = 0;

  // prologue: stage tile 0 -> buf0; prefetch tile_of(1) -> regs
  gload(0);
  *(ushort8*)&Ks[0][rs0 * 64 + so] = kp0;
  *(ushort8*)&Ks[0][rs1 * 64 + so] = kp1;
  *(ushort8*)&Vs[0][rs0 * 64 + so] = vp0;
  *(ushort8*)&Vs[0][rs1 * 64 + so] = vp1;
  gload(tile_of(1));
  __syncthreads();

  auto phase = [&](int qt, int qg, bf16x8 q0, bf16x8 q1, int ibase) {
    floatx4 O[4] = {};                           // O^T: row=hd(nt*16+quad*4+r), col=q(l16)
    floatx4 lac = {};                            // l via MFMA ones-row
    for (int kt = 0; kt <= qt; kt++) {
      const int i = ibase + kt;                  // global iter 0..32
      const u16* Kc = &Ks[pp][0];
      const u16* Vc = &Vs[pp][0];

      // ---- K frags from current buffer ----
      bf16x8 kf[4][2];
#pragma unroll
      for (int sub = 0; sub < 4; sub++) {
        const u16* kb = Kc + (sub * 16 + l16) * 64;
        kf[sub][0] = ld8(kb + x0);
        kf[sub][1] = ld8(kb + x1);
      }
      // ---- stage next tile into buf pp^1; prefetch tile after next ----
      if (i < 32) {
        *(ushort8*)&Ks[pp ^ 1][rs0 * 64 + so] = kp0;
        *(ushort8*)&Ks[pp ^ 1][rs1 * 64 + so] = kp1;
        *(ushort8*)&Vs[pp ^ 1][rs0 * 64 + so] = vp0;
        *(ushort8*)&Vs[pp ^ 1][rs1 * 64 + so] = vp1;
        if (i < 31) gload(tile_of(i + 2));
      }
      // ---- S^T = K*Q^T : 4 sub-tiles of 16 keys ----
      floatx4 sf[4];
#pragma unroll
      for (int sub = 0; sub < 4; sub++) {
        floatx4 s = {};
        s = mfma16(kf[sub][0], q0, s);           // A-frag: m=key, k=hd
        s = mfma16(kf[sub][1], q1, s);
        sf[sub] = s;
      }
      if (kt == qt) {                            // diagonal tile: mask key > q
#pragma unroll
        for (int sub = 0; sub < 4; sub++)
#pragma unroll
          for (int r = 0; r < 4; r++)
            if (kt * 64 + sub * 16 + quad * 4 + r > qg) sf[sub][r] = -INFINITY;
      }
      // ---- P = exp2(s'), pack to bf16 pairs ----
      u32x2 pk[4];
#pragma unroll
      for (int sub = 0; sub < 4; sub++) {
        pk[sub].x = pk2bf(__builtin_amdgcn_exp2f(sf[sub][0]), __builtin_amdgcn_exp2f(sf[sub][1]));
        pk[sub].y = pk2bf(__builtin_amdgcn_exp2f(sf[sub][2]), __builtin_amdgcn_exp2f(sf[sub][3]));
      }
      // ---- V frags from current buffer ----
      bf16x8 vf[4][2];
#pragma unroll
      for (int nt = 0; nt < 4; nt++) {
        const u16* vb = Vc + (nt * 16 + l16) * 64;
        vf[nt][0] = ld8(vb + x0);
        vf[nt][1] = ld8(vb + x1);
      }
      // ---- P^T to per-wave LDS scratch (swizzled b64 stores) ----
#pragma unroll
      for (int sub = 0; sub < 4; sub++) {
        const int slot = (2 * sub + (quad >> 1)) ^ (l16 & 7);
        *(u32x2*)&myP[l16 * 64 + slot * 8 + (quad & 1) * 4] = pk[sub];
      }
      asm volatile("s_waitcnt lgkmcnt(0)" ::: "memory");  // wave-local LDS write->read fence
      bf16x8 pf0 = ld8(&myP[l16 * 64 + x0]);     // B-frag: n=q, k=key 0..31
      bf16x8 pf1 = ld8(&myP[l16 * 64 + x1]);     //                key 32..63
      // ---- O^T += V^T * P^T ; l += ones * P^T (matrix pipe) ----
#pragma unroll
      for (int nt = 0; nt < 4; nt++) {
        O[nt] = mfma16(vf[nt][0], pf0, O[nt]);
        O[nt] = mfma16(vf[nt][1], pf1, O[nt]);
      }
      lac = mfma16(onesA, pf0, lac);
      lac = mfma16(onesA, pf1, lac);

      if (i < 32) {
        // LDS must be drained before waves cross (staging visibility); the prefetch
        // global_loads are register-destined and stay IN FLIGHT across the barrier.
        asm volatile("s_waitcnt lgkmcnt(0)" ::: "memory");
        __builtin_amdgcn_s_barrier();
        pp ^= 1;
      }
    }
    const float inv = 1.0f / lac[0];
    const size_t ooff = (size_t)qg * 2048 + h * HD_;
#pragma unroll
    for (int nt = 0; nt < 4; nt++)
#pragma unroll
      for (int r = 0; r < 4; r++)
        o[ooff + nt * 16 + quad * 4 + r] = f2bf(O[nt][r] * inv);
  };

  phase(p_, qgA, qfA0, qfA1, 0);                 // q-tile p_   (kt = 0..p_)
  phase(qtB, qgB, qfB0, qfB1, p_ + 1);           // q-tile 31-p_ (kt = 0..31-p_)
}

extern "C" void kernel_launch(void* const* d_in, const int* in_sizes, int n_in,
                              void* d_out, int out_size, void* d_ws, size_t ws_size,
                              hipStream_t stream) {
  const float* x  = (const float*)d_in[0];
  const float* fc = (const float*)d_in[1];
  const float* wq = (const float*)d_in[2];
  const float* wk = (const float*)d_in[3];
  const float* wv = (const float*)d_in[4];
  const float* wo = (const float*)d_in[5];
  float* out = (float*)d_out;

  // Workspace (30 MB), r9 layout. Lifetimes:
  //   [0,12)MB  qkv bf16: 2048 x 3072 (q|k|v), written by QKV gemm, read-only after rope
  //   [12,24)MB wb bf16: wq|wk|wv (3072 x 2048) — dead after QKV gemm
  //   [12,14)MB vT bf16 (after wb dead)
  //   [14,22)MB wob bf16 (cvt'd after QKV gemm)
  //   [22,30)MB ob bf16: attention output
  // x bf16 (8 MB) lives in d_out (16.8 MB) — overwritten by the final O-GEMM.
  char* ws = (char*)d_ws;
  const size_t MB = 1024 * 1024;
  u16* qkv = (u16*)(ws);
  u16* wb  = (u16*)(ws + 12 * MB);
  u16* vTb = (u16*)(ws + 12 * MB);
  u16* wob = (u16*)(ws + 14 * MB);
  u16* ob  = (u16*)(ws + 22 * MB);
  u16* xb  = (u16*)d_out;
  (void)ws_size; (void)n_in; (void)in_sizes; (void)out_size;

  // 1) x, wq|wk|wv -> bf16
  cvt_kernel<<<4096, 256, 0, stream>>>(x,  xb, 1048576);
  cvt_kernel<<<4096, 256, 0, stream>>>(wq, wb, 1048576);
  cvt_kernel<<<1024, 256, 0, stream>>>(wk, wb + (size_t)2048 * 2048, 262144);
  cvt_kernel<<<1024, 256, 0, stream>>>(wv, wb + (size_t)2560 * 2048, 262144);
  // 2) fused QKV projection (128x96, 512 blocks = 2/CU, 8 WAVES -> 16 waves/CU, XCD swz)
  gemm_db<128, 96, 1><<<dim3(32, 16), 512, 0, stream>>>(xb, wb, qkv, LDQ, 2048, 2048);
  // 3) wo -> bf16 (wb region dead now)
  cvt_kernel<<<4096, 256, 0, stream>>>(wo, wob, 1048576);
  // 4) RoPE: q pre-scaled by log2e/sqrt(HD); k unscaled
  rope_kernel<<<8192, 256, 0, stream>>>(qkv, fc, 5, LDQ, 0.18033688f);
  rope_kernel<<<2048, 256, 0, stream>>>(qkv + 2048, fc, 3, LDQ, 1.0f);
  // 5) V transpose
  transpose_v<<<4096, 256, 0, stream>>>(qkv, vTb);
  // 6) causal GQA flash attention -> ob (512 uniform 33-iter blocks, two-phase)
  attn_kernel<<<dim3(NH, 16), 256, 0, stream>>>(qkv, vTb, ob);
  // 7) output projection (128x64, 512 blocks, 8 waves, fp32 out, XCD swz) — overwrites xb
  gemm_db<128, 64, 0><<<dim3(32, 16), 512, 0, stream>>>(ob, wob, out, 2048, 2048, 2048);
}

// Round 15
// 201.303 us; speedup vs baseline: 1.1419x; 1.0688x over previous
//
#include <hip/hip_runtime.h>

typedef unsigned short u16;
typedef unsigned int u32;
typedef __bf16 bf16x8 __attribute__((ext_vector_type(8)));
typedef unsigned short ushort8 __attribute__((ext_vector_type(8)));
typedef float floatx4 __attribute__((ext_vector_type(4)));
typedef u32 u32x2 __attribute__((ext_vector_type(2)));

#define S_LEN 2048
#define NH 32
#define NKV 8
#define HD_ 64
#define LDQ 3072   // qkv row stride: [q 0..2047 | k 2048..2559 | v 2560..3071]

__device__ __forceinline__ u16 f2bf(float f) {
  unsigned u = __builtin_bit_cast(unsigned, f);
  u += 0x7FFF + ((u >> 16) & 1);   // round-to-nearest-even
  return (u16)(u >> 16);
}
__device__ __forceinline__ float bf2f(u16 h) {
  unsigned u = ((unsigned)h) << 16;
  return __builtin_bit_cast(float, u);
}
__device__ __forceinline__ bf16x8 ld8(const u16* p) {
  return __builtin_bit_cast(bf16x8, *(const ushort8*)p);
}
__device__ __forceinline__ floatx4 mfma16(bf16x8 a, bf16x8 b, floatx4 c) {
  return __builtin_amdgcn_mfma_f32_16x16x32_bf16(a, b, c, 0, 0, 0);
}
// two fp32 -> packed bf16 pair (round-half-up via +0x8000, then byte-perm)
__device__ __forceinline__ u32 pk2bf(float a, float b) {
  u32 ua = __builtin_bit_cast(u32, a) + 0x8000u;
  u32 ub = __builtin_bit_cast(u32, b) + 0x8000u;
  return __builtin_amdgcn_perm(ub, ua, 0x07060302);   // [bf(a) | bf(b)<<16]
}
__device__ __forceinline__ ushort4 cvt4f(float4 v) {
  return make_ushort4(f2bf(v.x), f2bf(v.y), f2bf(v.z), f2bf(v.w));
}

// ---------------- fused converts: x | wq | wk | wv -> bf16, ONE launch ----------------
// r15 node-count reduction (11 -> 5): r10 measured ~6.4us of wall per deleted graph
// node. Unlike r7/r8's crashing multi-range else-chain kernels, this is STRAIGHT-LINE:
// every thread executes every section with a simple i<n guard — no per-block pointer
// selection. gemm/attn are untouched (fusion into the gemm is proven-bad: r10/r13).
__global__ void cvt4_kernel(const float* __restrict__ x, const float* __restrict__ wq,
                            const float* __restrict__ wk, const float* __restrict__ wv,
                            u16* __restrict__ xb, u16* __restrict__ wb) {
  const int i = blockIdx.x * blockDim.x + threadIdx.x;   // grid covers 1048576 exactly
  ((ushort4*)xb)[i] = cvt4f(((const float4*)x)[i]);      // x: 1M float4
  ((ushort4*)wb)[i] = cvt4f(((const float4*)wq)[i]);     // wq: 1M float4
  if (i < 262144) {                                      // wk: 256K float4
    ((ushort4*)(wb + (size_t)2048 * 2048))[i] = cvt4f(((const float4*)wk)[i]);
    ((ushort4*)(wb + (size_t)2560 * 2048))[i] = cvt4f(((const float4*)wv)[i]);
  }
}

// ---------------- fused mid: rope(q+k, unified) | wo-cvt | V-transpose, ONE launch -----
// Runs after the QKV gemm. Rope q/k unified: 40 heads (32 q + 8 k) at cols hh*64, one
// formula, only the scale is selected (q cols get log2e/sqrt(HD)). hh = i>>16 (S*32 =
// 65536 pairs per head), s = (i>>5)&2047, d = i&31 — no division, coalesced (4B/thread).
// Transpose reads v cols (>=2560), rope writes q/k cols (<2560): disjoint, no ordering
// hazard even across blocks. wo-cvt targets wob (wb region dead after the gemm).
__global__ void mid_kernel(u16* qkv, const float* __restrict__ fc,
                           const float* __restrict__ wo, u16* __restrict__ wob,
                           u16* __restrict__ vT) {
  const int i = blockIdx.x * blockDim.x + threadIdx.x;   // grid covers 2621440 exactly
  {                                                      // rope: 40 heads x 2048 s x 32 d
    const int hh = i >> 16, s = (i >> 5) & 2047, d = i & 31;
    const float c  = fc[s * 64 + d * 2];
    const float sn = fc[s * 64 + d * 2 + 1];
    const float scale = (hh < 32) ? 0.18033688f : 1.0f;  // q: log2e/sqrt(HD); k: 1
    const size_t base = (size_t)s * LDQ + hh * 64 + d * 2;
    const float x0 = bf2f(qkv[base]), x1 = bf2f(qkv[base + 1]);
    qkv[base]     = f2bf((x0 * c - x1 * sn) * scale);
    qkv[base + 1] = f2bf((x0 * sn + x1 * c) * scale);
  }
  if (i < 1048576) {                                     // wo -> bf16 (1M float4)
    ((ushort4*)wob)[i] = cvt4f(((const float4*)wo)[i]);
  }
  if (i < 1048576) {                                     // vT[(g*64+hd)][s] <- qkv v-cols
    const int s = i & (S_LEN - 1), t = i >> 11;
    vT[i] = qkv[(size_t)s * LDQ + 2560 + t];
  }
}

// ---------------- Double-buffered GEMM: C[M][N] = A[M][K] @ B[N][K]^T (bf16 in) ------------
// r14-proven: 8-WAVE (512-thread) blocks, 128x96 / 128x64 tiles. 4-wave was 4x
// stall-dominated with 2 waves/SIMD; 8 waves doubles waves/CU to 16 (LDS 57KB still
// 2 blocks/CU). Wave grid 4x2; staging thread t owns rows {crow, crow+64}. Chunk-XOR
// conflict-free LDS, reg-staged prefetch, one barrier/iter, XCD-chunked block swizzle.
// KEEP PURE: fusion into this kernel is proven-bad (r10 fp32-staging 2x; r13 rope
// epilogue +35% via regalloc).
template <int TM, int TN, int OUT_BF16>
__global__ __launch_bounds__(512) void gemm_db(
    const u16* __restrict__ A, const u16* __restrict__ B, void* __restrict__ C,
    int ldc, int K, int lda) {
  __shared__ __align__(16) u16 As[2][TM * 64];
  __shared__ __align__(16) u16 Bs[2][TN * 64];
  const int tid = threadIdx.x;
  const int wave = tid >> 6, lane = tid & 63;
  const int quad = lane >> 4, l16 = lane & 15;
  const int nwg = gridDim.x * gridDim.y;
  int lin = (int)blockIdx.y * gridDim.x + blockIdx.x;
  lin = (lin & 7) * (nwg >> 3) + (lin >> 3);     // XCD-chunked bijective remap
  const int bm = (lin % gridDim.y) * TM, bn = (lin / gridDim.y) * TN;
  const int wr = (wave >> 1) * (TM / 4);         // 4 wave-rows of TM/4
  const int wc = (wave & 1) * (TN / 2);          // 2 wave-cols of TN/2
  constexpr int MI = TM / 64, NI = TN / 32;      // per-wave 16x16 frags: MI x NI
  constexpr int BX = (TN > 64) ? 1 : 0;          // B second staging group exists?
  const int crow = tid >> 3, col8 = tid & 7;     // staging: row 0..63, 8-elem col chunk

  size_t aoff[2], boff[2];
#pragma unroll
  for (int j = 0; j < 2; j++) aoff[j] = (size_t)(bm + crow + j * 64) * lda + col8 * 8;
  boff[0] = (size_t)(bn + crow) * K + col8 * 8;
  boff[1] = (size_t)(bn + crow + 64) * K + col8 * 8;   // only used when crow < TN-64
  const bool bAct = BX && (crow < TN - 64);      // wave-uniform: crow<32 <=> waves 0..3

  ushort8 a8[2], b8[2];
  auto load_tiles = [&](int k0) {
#pragma unroll
    for (int j = 0; j < 2; j++) a8[j] = *(const ushort8*)(A + aoff[j] + k0);
    b8[0] = *(const ushort8*)(B + boff[0] + k0);
    if (bAct) b8[1] = *(const ushort8*)(B + boff[1] + k0);
  };
  const int sw = (col8 ^ (crow & 7)) * 8;        // swizzled chunk (same for row, row+64)
  auto write_tiles = [&](int p) {
#pragma unroll
    for (int j = 0; j < 2; j++)
      *(ushort8*)&As[p][(crow + j * 64) * 64 + sw] = a8[j];
    *(ushort8*)&Bs[p][crow * 64 + sw] = b8[0];
    if (bAct) *(ushort8*)&Bs[p][(crow + 64) * 64 + sw] = b8[1];
  };

  floatx4 acc[MI][NI] = {};
  load_tiles(0);
  write_tiles(0);
  __syncthreads();
  int p = 0;
  for (int k0 = 0; k0 < K; k0 += 64) {
    const bool more = (k0 + 64 < K);
    if (more) load_tiles(k0 + 64);               // prefetch next tile (covered by compute)
#pragma unroll
    for (int kh = 0; kh < 2; kh++) {
      bf16x8 af[MI], bfr[NI];
#pragma unroll
      for (int mi = 0; mi < MI; mi++) {
        const int row = wr + mi * 16 + l16;
        af[mi] = ld8(&As[p][row * 64 + (((kh * 4 + quad) ^ (row & 7)) * 8)]);
      }
#pragma unroll
      for (int ni = 0; ni < NI; ni++) {
        const int row = wc + ni * 16 + l16;
        bfr[ni] = ld8(&Bs[p][row * 64 + (((kh * 4 + quad) ^ (row & 7)) * 8)]);
      }
#pragma unroll
      for (int mi = 0; mi < MI; mi++)
#pragma unroll
        for (int ni = 0; ni < NI; ni++)
          acc[mi][ni] = mfma16(af[mi], bfr[ni], acc[mi][ni]);
    }
    if (more) {
      write_tiles(p ^ 1);                        // vmcnt wait lands here, post-compute
      __syncthreads();                           // one barrier per iter
      p ^= 1;
    }
  }

#pragma unroll
  for (int mi = 0; mi < MI; mi++)
#pragma unroll
    for (int ni = 0; ni < NI; ni++)
#pragma unroll
      for (int r = 0; r < 4; r++) {
        const int row = bm + wr + mi * 16 + quad * 4 + r;   // C/D: row=(lane>>4)*4+reg
        const int col = bn + wc + ni * 16 + l16;            //      col=lane&15
        if (OUT_BF16) ((u16*)C)[(size_t)row * ldc + col] = f2bf(acc[mi][ni][r]);
        else          ((float*)C)[(size_t)row * ldc + col] = acc[mi][ni][r];
      }
}

// ---------------- Flash attention (causal, GQA) — r5 structure (measured best) ------------
// r2's two-phase uniform schedule (block (h,p) runs q-tiles p then 31-p, exactly 33 iters
// per block) + r3's conflict-free chunk-XOR stride-64 LDS + K/V double-buffer with ONE RAW
// s_barrier per iter (lgkmcnt(0) only; prefetch global_loads are register-destined and
// stay in flight across the barrier).
__global__ __launch_bounds__(256) void attn_kernel(const u16* qkv, const u16* __restrict__ vT,
                                                   u16* __restrict__ o) {
  __shared__ __align__(16) u16 Ks[2][64 * 64];   // [key][hd], chunk-XOR swizzled
  __shared__ __align__(16) u16 Vs[2][64 * 64];   // [hd][key], chunk-XOR swizzled
  __shared__ __align__(16) u16 pS[4][16 * 64];   // per-wave P^T scratch (reused A/B)
  const int h = blockIdx.x;
  const int g = h >> 2;                          // kv head
  const int tid = threadIdx.x;
  const int wave = tid >> 6, lane = tid & 63;
  const int quad = lane >> 4, l16 = lane & 15;
  const int p_ = (int)blockIdx.y;                // 0..15
  const int qtB = 31 - p_;                       // pair (p_, 31-p_): 33 iters total

  const ushort8 ones_u = {0x3F80, 0x3F80, 0x3F80, 0x3F80, 0x3F80, 0x3F80, 0x3F80, 0x3F80};
  const bf16x8 onesA = __builtin_bit_cast(bf16x8, ones_u);

  const int qrow = wave * 16 + l16;
  const int qgA = p_ * 64 + qrow, qgB = qtB * 64 + qrow;
  const size_t qoffA = (size_t)qgA * LDQ + h * HD_;
  const size_t qoffB = (size_t)qgB * LDQ + h * HD_;
  bf16x8 qfA0 = ld8(qkv + qoffA + quad * 8);     // B-frag: n=q, k=hd (pre-scaled log2e/8)
  bf16x8 qfA1 = ld8(qkv + qoffA + 32 + quad * 8);
  bf16x8 qfB0 = ld8(qkv + qoffB + quad * 8);
  bf16x8 qfB1 = ld8(qkv + qoffB + 32 + quad * 8);

  // staging: thread owns rows {rs0, rs0+32}, chunk col8; swizzled slot col8^(row&7)
  const int rs0 = tid >> 3, rs1 = rs0 + 32;
  const int col8 = tid & 7;
  const int so = (col8 ^ (rs0 & 7)) * 8;         // swizzled u16 offset within row
  const int o0 = col8 * 8;                       // global col offset
  // lane-constant swizzled chunk offsets for all frag reads (chunks quad and 4+quad)
  const int x0 = (quad ^ (l16 & 7)) * 8;
  const int x1 = ((4 + quad) ^ (l16 & 7)) * 8;
  const u16* ksrc = qkv + 2048 + g * HD_;        // row stride LDQ
  const u16* vsrc = vT + (size_t)g * HD_ * S_LEN;// row stride S_LEN

  ushort8 kp0, kp1, vp0, vp1;
  auto gload = [&](int t) {                      // tile t -> regs
    const int tb = t * 64;
    kp0 = *(const ushort8*)(ksrc + (size_t)(tb + rs0) * LDQ + o0);
    kp1 = *(const ushort8*)(ksrc + (size_t)(tb + rs1) * LDQ + o0);
    vp0 = *(const ushort8*)(vsrc + (size_t)rs0 * S_LEN + tb + o0);
    vp1 = *(const ushort8*)(vsrc + (size_t)rs1 * S_LEN + tb + o0);
  };
  auto tile_of = [&](int i) { return (i <= p_) ? i : (i - p_ - 1); };

  u16* myP = &pS[wave][0];
  int pp = 0;

  // prologue: stage tile 0 -> buf0; prefetch tile_of(1) -> regs
  gload(0);
  *(ushort8*)&Ks[0][rs0 * 64 + so] = kp0;
  *(ushort8*)&Ks[0][rs1 * 64 + so] = kp1;
  *(ushort8*)&Vs[0][rs0 * 64 + so] = vp0;
  *(ushort8*)&Vs[0][rs1 * 64 + so] = vp1;
  gload(tile_of(1));
  __syncthreads();

  auto phase = [&](int qt, int qg, bf16x8 q0, bf16x8 q1, int ibase) {
    floatx4 O[4] = {};                           // O^T: row=hd(nt*16+quad*4+r), col=q(l16)
    floatx4 lac = {};                            // l via MFMA ones-row
    for (int kt = 0; kt <= qt; kt++) {
      const int i = ibase + kt;                  // global iter 0..32
      const u16* Kc = &Ks[pp][0];
      const u16* Vc = &Vs[pp][0];

      // ---- K frags from current buffer ----
      bf16x8 kf[4][2];
#pragma unroll
      for (int sub = 0; sub < 4; sub++) {
        const u16* kb = Kc + (sub * 16 + l16) * 64;
        kf[sub][0] = ld8(kb + x0);
        kf[sub][1] = ld8(kb + x1);
      }
      // ---- stage next tile into buf pp^1; prefetch tile after next ----
      if (i < 32) {
        *(ushort8*)&Ks[pp ^ 1][rs0 * 64 + so] = kp0;
        *(ushort8*)&Ks[pp ^ 1][rs1 * 64 + so] = kp1;
        *(ushort8*)&Vs[pp ^ 1][rs0 * 64 + so] = vp0;
        *(ushort8*)&Vs[pp ^ 1][rs1 * 64 + so] = vp1;
        if (i < 31) gload(tile_of(i + 2));
      }
      // ---- S^T = K*Q^T : 4 sub-tiles of 16 keys ----
      floatx4 sf[4];
#pragma unroll
      for (int sub = 0; sub < 4; sub++) {
        floatx4 s = {};
        s = mfma16(kf[sub][0], q0, s);           // A-frag: m=key, k=hd
        s = mfma16(kf[sub][1], q1, s);
        sf[sub] = s;
      }
      if (kt == qt) {                            // diagonal tile: mask key > q
#pragma unroll
        for (int sub = 0; sub < 4; sub++)
#pragma unroll
          for (int r = 0; r < 4; r++)
            if (kt * 64 + sub * 16 + quad * 4 + r > qg) sf[sub][r] = -INFINITY;
      }
      // ---- P = exp2(s'), pack to bf16 pairs ----
      u32x2 pk[4];
#pragma unroll
      for (int sub = 0; sub < 4; sub++) {
        pk[sub].x = pk2bf(__builtin_amdgcn_exp2f(sf[sub][0]), __builtin_amdgcn_exp2f(sf[sub][1]));
        pk[sub].y = pk2bf(__builtin_amdgcn_exp2f(sf[sub][2]), __builtin_amdgcn_exp2f(sf[sub][3]));
      }
      // ---- V frags from current buffer ----
      bf16x8 vf[4][2];
#pragma unroll
      for (int nt = 0; nt < 4; nt++) {
        const u16* vb = Vc + (nt * 16 + l16) * 64;
        vf[nt][0] = ld8(vb + x0);
        vf[nt][1] = ld8(vb + x1);
      }
      // ---- P^T to per-wave LDS scratch (swizzled b64 stores) ----
#pragma unroll
      for (int sub = 0; sub < 4; sub++) {
        const int slot = (2 * sub + (quad >> 1)) ^ (l16 & 7);
        *(u32x2*)&myP[l16 * 64 + slot * 8 + (quad & 1) * 4] = pk[sub];
      }
      asm volatile("s_waitcnt lgkmcnt(0)" ::: "memory");  // wave-local LDS write->read fence
      bf16x8 pf0 = ld8(&myP[l16 * 64 + x0]);     // B-frag: n=q, k=key 0..31
      bf16x8 pf1 = ld8(&myP[l16 * 64 + x1]);     //                key 32..63
      // ---- O^T += V^T * P^T ; l += ones * P^T (matrix pipe) ----
#pragma unroll
      for (int nt = 0; nt < 4; nt++) {
        O[nt] = mfma16(vf[nt][0], pf0, O[nt]);
        O[nt] = mfma16(vf[nt][1], pf1, O[nt]);
      }
      lac = mfma16(onesA, pf0, lac);
      lac = mfma16(onesA, pf1, lac);

      if (i < 32) {
        // LDS must be drained before waves cross (staging visibility); the prefetch
        // global_loads are register-destined and stay IN FLIGHT across the barrier.
        asm volatile("s_waitcnt lgkmcnt(0)" ::: "memory");
        __builtin_amdgcn_s_barrier();
        pp ^= 1;
      }
    }
    const float inv = 1.0f / lac[0];
    const size_t ooff = (size_t)qg * 2048 + h * HD_;
#pragma unroll
    for (int nt = 0; nt < 4; nt++)
#pragma unroll
      for (int r = 0; r < 4; r++)
        o[ooff + nt * 16 + quad * 4 + r] = f2bf(O[nt][r] * inv);
  };

  phase(p_, qgA, qfA0, qfA1, 0);                 // q-tile p_   (kt = 0..p_)
  phase(qtB, qgB, qfB0, qfB1, p_ + 1);           // q-tile 31-p_ (kt = 0..31-p_)
}

extern "C" void kernel_launch(void* const* d_in, const int* in_sizes, int n_in,
                              void* d_out, int out_size, void* d_ws, size_t ws_size,
                              hipStream_t stream) {
  const float* x  = (const float*)d_in[0];
  const float* fc = (const float*)d_in[1];
  const float* wq = (const float*)d_in[2];
  const float* wk = (const float*)d_in[3];
  const float* wv = (const float*)d_in[4];
  const float* wo = (const float*)d_in[5];
  float* out = (float*)d_out;

  // Workspace (30 MB), r9/r14 layout. Lifetimes:
  //   [0,12)MB  qkv bf16: 2048 x 3072 (q|k|v), written by QKV gemm, rope'd by mid
  //   [12,24)MB wb bf16: wq|wk|wv (3072 x 2048) — dead after QKV gemm
  //   [12,14)MB vT bf16 (after wb dead)
  //   [14,22)MB wob bf16 (cvt'd by mid, after QKV gemm)
  //   [22,30)MB ob bf16: attention output
  // x bf16 (8 MB) lives in d_out (16.8 MB) — overwritten by the final O-GEMM.
  char* ws = (char*)d_ws;
  const size_t MB = 1024 * 1024;
  u16* qkv = (u16*)(ws);
  u16* wb  = (u16*)(ws + 12 * MB);
  u16* vTb = (u16*)(ws + 12 * MB);
  u16* wob = (u16*)(ws + 14 * MB);
  u16* ob  = (u16*)(ws + 22 * MB);
  u16* xb  = (u16*)d_out;
  (void)ws_size; (void)n_in; (void)in_sizes; (void)out_size;

  // 1) fused converts: x | wq | wk | wv -> bf16 (ONE launch, straight-line guarded)
  cvt4_kernel<<<4096, 256, 0, stream>>>(x, wq, wk, wv, xb, wb);
  // 2) fused QKV projection (128x96, 512 blocks = 2/CU, 8 waves -> 16 waves/CU, XCD swz)
  gemm_db<128, 96, 1><<<dim3(32, 16), 512, 0, stream>>>(xb, wb, qkv, LDQ, 2048, 2048);
  // 3) fused mid: rope(q+k unified) | wo-cvt | V-transpose (ONE launch)
  mid_kernel<<<10240, 256, 0, stream>>>(qkv, fc, wo, wob, vTb);
  // 4) causal GQA flash attention -> ob (512 uniform 33-iter blocks, two-phase)
  attn_kernel<<<dim3(NH, 16), 256, 0, stream>>>(qkv, vTb, ob);
  // 5) output projection (128x64, 512 blocks, 8 waves, fp32 out, XCD swz) — overwrites xb
  gemm_db<128, 64, 0><<<dim3(32, 16), 512, 0, stream>>>(ob, wob, out, 2048, 2048, 2048);
}